// Round 18
// baseline (228.792 us; speedup 1.0000x reference)
//
#include <hip/hip_runtime.h>

namespace {
constexpr int H = 544, W = 960, D = 64, NB = 2;
constexpr long SL      = (long)H * W;     // per-batch image elems
constexpr long SLICE_B = (long)NB * SL * 4;
constexpr long W64     = (long)W * 64;    // out1 floats per (b,y) row = 61440
}

// ===========================================================================
// Bitwise replica of XLA ReduceWindowRewriter base-16 cumsum (verified
// r12-r17). out1 layout is now QUAD-PACKED: [b][y][x/4][d][4] (float4 per
// (x-quad, d)); pure addressing change, all arithmetic orders unchanged.
// ===========================================================================

__device__ __forceinline__ void fold16(float& o1p, float& o2, int& c, int& a,
                                       float tot) {
  o1p = (c == 0) ? tot : (o1p + tot);
  if (++c == 16) { o2 = (a == 0) ? o1p : (o2 + o1p); ++a; c = 0; }
}
__device__ __forceinline__ float baseof(float o1p, float o2, int c, int a) {
  return (a == 0) ? ((c == 0) ? 0.f : o1p) : ((c == 0) ? o2 : (o2 + o1p));
}

#define TILE_FULL()                                                          \
  {                                                                          \
    const float base =                                                       \
        (a == 0) ? ((c == 0) ? 0.f : o1p) : ((c == 0) ? o2 : (o2 + o1p));    \
    float ip = wc[0];                                                        \
    oc_[0] = base + ip;                                                      \
    _Pragma("unroll") for (int j = 1; j < 16; ++j) {                         \
      ip += wc[j];                                                           \
      oc_[j] = base + ip;                                                    \
    }                                                                        \
    o1p = (c == 0) ? ip : (o1p + ip);                                        \
    if (++c == 16) { o2 = (a == 0) ? o1p : (o2 + o1p); ++a; c = 0; }         \
  }

#define TILE_PART14()                                                        \
  {                                                                          \
    const float base =                                                       \
        (a == 0) ? ((c == 0) ? 0.f : o1p) : ((c == 0) ? o2 : (o2 + o1p));    \
    float ip = wc[0];                                                        \
    oc_[0] = base + ip;                                                      \
    _Pragma("unroll") for (int j = 1; j < 14; ++j) {                         \
      ip += wc[j];                                                           \
      oc_[j] = base + ip;                                                    \
    }                                                                        \
  }

#define ROT()                                                                \
  _Pragma("unroll") for (int j = 0; j < 16; ++j) {                           \
    op_[j] = oc_[j];                                                         \
    wc[j] = wn[j];                                                           \
  }

// ---------------------------------------------------------------------------
// Phase 1: vertical box -> out1 quad-packed. Thread = (b, x, lane=d).
// Identical to verified r13/r17 kernel except the store address formula.
// Block = 4 waves = x, x+1, x+2, x+3 (the 4 phases of one x-quad) -> the
// 1KB quad region is filled dense within the block (L2 sector merge).
// ---------------------------------------------------------------------------
__global__ __launch_bounds__(256) void vbox_t(
    const float* __restrict__ Lp, const float* __restrict__ Rp,
    float* __restrict__ out1) {
  const int t  = blockIdx.x * 256 + threadIdx.x;
  const int dc = t & 63;
  const int rs = t >> 6;
  const int x  = rs % W;
  const int b  = rs / W;
  const int xs = max(x - dc, 0);
  const float* Lc = Lp + (long)b * SL + x;
  const float* Rc = Rp + (long)b * SL + xs;
  // quad-packed: float idx = (b*H+e)*W64 + (x>>2)*256 + dc*4 + (x&3)
  float* Ob = out1 + (long)b * H * W64 + (long)(x >> 2) * 256 + dc * 4 + (x & 3);

  float o1p = 0.f, o2 = 0.f;
  int c = 0, a = 0;
  float wc[16], wn[16], oc_[16], op_[16];

#pragma unroll
  for (int j = 0; j < 16; ++j) {
    const long yy = j - 7;
    wc[j] = (j >= 7) ? fabsf(Lc[yy * W] - Rc[yy * W]) : 0.f;
  }
#pragma unroll
  for (int j = 0; j < 16; ++j) {
    const long yy = 9 + j;
    wn[j] = fabsf(Lc[yy * W] - Rc[yy * W]);
  }
  TILE_FULL();
  Ob[0]   = oc_[14];
  Ob[W64] = oc_[15] - oc_[0];
  ROT();

#pragma unroll 1
  for (int tt = 1; tt <= 32; ++tt) {
#pragma unroll
    for (int j = 0; j < 16; ++j) {
      const long yy = 16 * (tt + 1) + j - 7;
      wn[j] = fabsf(Lc[yy * W] - Rc[yy * W]);
    }
    TILE_FULL();
#pragma unroll
    for (int j = 0; j < 16; ++j) {
      const float lo = (j < 15) ? op_[j + 1] : oc_[0];
      const long e = 16 * tt + j - 14;
      Ob[e * W64] = oc_[j] - lo;
    }
    ROT();
  }

#pragma unroll
  for (int j = 0; j < 16; ++j) {
    const long yy = 537 + j;
    wn[j] = (j <= 6) ? fabsf(Lc[yy * W] - Rc[yy * W]) : 0.f;
  }
  TILE_FULL();
#pragma unroll
  for (int j = 0; j < 16; ++j) {
    const float lo = (j < 15) ? op_[j + 1] : oc_[0];
    const long e = 16 * 33 + j - 14;
    Ob[e * W64] = oc_[j] - lo;
  }
  ROT();

  TILE_PART14();
#pragma unroll
  for (int j = 0; j < 14; ++j) {
    const long e = 530 + j;
    Ob[e * W64] = oc_[j] - op_[j + 1];
  }
}

// ---------------------------------------------------------------------------
// Phase 2: horizontal box + argmin. Block = (y, b), 8 waves (512 thr); lane=d.
// Same verified structure as r17; generic tiles now load 5 float4 quads
// (16 B/lane, 1 KB/wave) instead of 16 scalar 256 B loads.
// ---------------------------------------------------------------------------
__global__ __launch_bounds__(512) void hbox_p8(
    const float* __restrict__ out1, int* __restrict__ out) {
  __shared__ float T[61][64];
  const int lane = threadIdx.x & 63;
  const int w    = threadIdx.x >> 6;
  const int y = blockIdx.x, b = blockIdx.y;
  const float* __restrict__ rowbase = out1 + (long)(b * H + y) * W64;
  const float4* __restrict__ rowq = (const float4*)rowbase;
  int* __restrict__ orow = out + (long)b * SL + (long)y * W;

  auto val = [&](int q) -> float {               // scalar fallback (edge tiles)
    const int xsrc = q - 7;
    return (xsrc >= 0 && xsrc < W)
             ? rowbase[(long)(xsrc >> 2) * 256 + lane * 4 + (xsrc & 3)]
             : 0.f;
  };
  auto load16q = [&](int t, float (&vv)[16]) {   // generic tiles 1..59
    float4 f[5];
#pragma unroll
    for (int k = 0; k < 5; ++k) f[k] = rowq[(long)(4 * t - 2 + k) * 64 + lane];
    vv[0] = f[0].y;  vv[1] = f[0].z;  vv[2] = f[0].w;
    vv[3] = f[1].x;  vv[4] = f[1].y;  vv[5] = f[1].z;  vv[6] = f[1].w;
    vv[7] = f[2].x;  vv[8] = f[2].y;  vv[9] = f[2].z;  vv[10] = f[2].w;
    vv[11] = f[3].x; vv[12] = f[3].y; vv[13] = f[3].z; vv[14] = f[3].w;
    vv[15] = f[4].x;
  };

  const int t0   = (w < 5) ? 8 * w : 40 + 7 * (w - 5);   // 0,8,16,24,32,40,47,54
  const int tend = t0 + ((w < 5) ? 8 : 7);

  // ---- phase A: owned-tile totals (identical 16-add order) ----
  for (int t = t0; t < tend; ++t) {
    float vv[16];
    if (t >= 1 && t <= 59) {
      load16q(t, vv);
    } else {
#pragma unroll
      for (int j = 0; j < 16; ++j) vv[j] = val(16 * t + j);
    }
    float s = vv[0];
#pragma unroll
    for (int j = 1; j < 16; ++j) s += vv[j];
    T[t][lane] = s;
  }
  __syncthreads();

  // ---- phase B: replay fold to entry state ----
  float o1p = 0.f, o2 = 0.f;
  int c = 0, a = 0;
  for (int tp = 0; tp + 1 < t0; ++tp) fold16(o1p, o2, c, a, T[tp][lane]);

  float poc[16];
  if (w > 0) {                       // recompute tile t0-1 scan (t0-1 in 7..53)
    const float base_prev = baseof(o1p, o2, c, a);
    fold16(o1p, o2, c, a, T[t0 - 1][lane]);
    float vv[16];
    load16q(t0 - 1, vv);
    float ipp = vv[0];
    poc[0] = base_prev + ipp;
#pragma unroll
    for (int j = 1; j < 16; ++j) { ipp += vv[j]; poc[j] = base_prev + ipp; }
  }
  float base = baseof(o1p, o2, c, a);

  for (int t = t0; t < tend; ++t) {
    float vv[16];
    if (t >= 1 && t <= 59) {
      load16q(t, vv);
    } else {
#pragma unroll
      for (int j = 0; j < 16; ++j) vv[j] = val(16 * t + j);
    }
    float oc_[16];
    float ip = vv[0];
    oc_[0] = base + ip;
#pragma unroll
    for (int j = 1; j < 16; ++j) { ip += vv[j]; oc_[j] = base + ip; }

    if (t == 0) {
      const float c0 = oc_[14], c1 = oc_[15] - oc_[0];   // e = 0, 1
      float m0 = c0, m1 = c1;
#pragma unroll
      for (int s = 0; s < 6; ++s) {
        const int off = 1 << s;
        m0 = fminf(m0, __shfl_xor(m0, off));
        m1 = fminf(m1, __shfl_xor(m1, off));
      }
      const int d0 = __ffsll((unsigned long long)__ballot(c0 == m0)) - 1;
      const int d1 = __ffsll((unsigned long long)__ballot(c1 == m1)) - 1;
      const int res = (lane == 0) ? d0 : d1;
      if (lane < 2) orow[lane] = res;
    } else if (t == 60) {                          // partial: e = 946..959
      float bc[14], mn[14];
#pragma unroll
      for (int j = 0; j < 14; ++j) { bc[j] = oc_[j] - poc[j + 1]; mn[j] = bc[j]; }
#pragma unroll
      for (int s = 0; s < 6; ++s) {
        const int off = 1 << s;
#pragma unroll
        for (int j = 0; j < 14; ++j) mn[j] = fminf(mn[j], __shfl_xor(mn[j], off));
      }
      int res = 0;
#pragma unroll
      for (int j = 0; j < 14; ++j) {
        const int dj = __ffsll((unsigned long long)__ballot(bc[j] == mn[j])) - 1;
        res = (lane == j) ? dj : res;
      }
      if (lane < 14) orow[946 + lane] = res;
    } else {
      float bc[16], mn[16];
#pragma unroll
      for (int j = 0; j < 16; ++j) {
        bc[j] = oc_[j] - ((j < 15) ? poc[j + 1] : oc_[0]);
        mn[j] = bc[j];
      }
#pragma unroll
      for (int s = 0; s < 6; ++s) {
        const int off = 1 << s;
#pragma unroll
        for (int j = 0; j < 16; ++j) mn[j] = fminf(mn[j], __shfl_xor(mn[j], off));
      }
      int res = 0;
#pragma unroll
      for (int j = 0; j < 16; ++j) {
        const int dj = __ffsll((unsigned long long)__ballot(bc[j] == mn[j])) - 1;
        res = (lane == j) ? dj : res;
      }
      if (lane < 16) orow[16 * t - 14 + lane] = res;
    }

    if (t + 1 < tend) {
      fold16(o1p, o2, c, a, ip);
      base = baseof(o1p, o2, c, a);
#pragma unroll
      for (int j = 0; j < 16; ++j) poc[j] = oc_[j];
    }
  }
}

extern "C" void kernel_launch(void* const* d_in, const int* in_sizes, int n_in,
                              void* d_out, int out_size, void* d_ws, size_t ws_size,
                              hipStream_t stream) {
  const float* L = (const float*)d_in[0];
  const float* R = (const float*)d_in[1];
  int* out = (int*)d_out;
  if (ws_size < (size_t)(D * SLICE_B)) return;   // direct path confirmed in r12
  float* out1 = (float*)d_ws;

  vbox_t<<<(NB * W * 64) / 256, 256, 0, stream>>>(L, R, out1);
  hbox_p8<<<dim3(H, NB), 512, 0, stream>>>(out1, out);
}

// Round 19
// 200.348 us; speedup vs baseline: 1.1420x; 1.1420x over previous
//
#include <hip/hip_runtime.h>

namespace {
constexpr int H = 544, W = 960, D = 64, NB = 2;
constexpr long SL      = (long)H * W;     // per-batch image elems
constexpr long SLICE_B = (long)NB * SL * 4;
constexpr long W64     = (long)W * 64;    // row stride in out1 elems
}

// ===========================================================================
// Bitwise replica of XLA ReduceWindowRewriter base-16 cumsum (verified
// r12-r18). Linear out1 layout [b][y][x][d] (r13-verified fast paths).
// ===========================================================================

__device__ __forceinline__ void fold16(float& o1p, float& o2, int& c, int& a,
                                       float tot) {
  o1p = (c == 0) ? tot : (o1p + tot);
  if (++c == 16) { o2 = (a == 0) ? o1p : (o2 + o1p); ++a; c = 0; }
}
__device__ __forceinline__ float baseof(float o1p, float o2, int c, int a) {
  return (a == 0) ? ((c == 0) ? 0.f : o1p) : ((c == 0) ? o2 : (o2 + o1p));
}

#define TILE_FULL()                                                          \
  {                                                                          \
    const float base =                                                       \
        (a == 0) ? ((c == 0) ? 0.f : o1p) : ((c == 0) ? o2 : (o2 + o1p));    \
    float ip = wc[0];                                                        \
    oc_[0] = base + ip;                                                      \
    _Pragma("unroll") for (int j = 1; j < 16; ++j) {                         \
      ip += wc[j];                                                           \
      oc_[j] = base + ip;                                                    \
    }                                                                        \
    o1p = (c == 0) ? ip : (o1p + ip);                                        \
    if (++c == 16) { o2 = (a == 0) ? o1p : (o2 + o1p); ++a; c = 0; }         \
  }

#define TILE_PART14()                                                        \
  {                                                                          \
    const float base =                                                       \
        (a == 0) ? ((c == 0) ? 0.f : o1p) : ((c == 0) ? o2 : (o2 + o1p));    \
    float ip = wc[0];                                                        \
    oc_[0] = base + ip;                                                      \
    _Pragma("unroll") for (int j = 1; j < 14; ++j) {                         \
      ip += wc[j];                                                           \
      oc_[j] = base + ip;                                                    \
    }                                                                        \
  }

#define ROT()                                                                \
  _Pragma("unroll") for (int j = 0; j < 16; ++j) {                           \
    op_[j] = oc_[j];                                                         \
    wc[j] = wn[j];                                                           \
  }

// ---------------------------------------------------------------------------
// Phase 1: vertical box -> out1[b][y][x][d]. Thread = (b, x, lane=d).
// Verbatim r13 kernel (verified 74 us @ 3.6 TB/s dense writes).
// ---------------------------------------------------------------------------
__global__ __launch_bounds__(256) void vbox_t(
    const float* __restrict__ Lp, const float* __restrict__ Rp,
    float* __restrict__ out1) {
  const int t  = blockIdx.x * 256 + threadIdx.x;
  const int dc = t & 63;
  const int rs = t >> 6;
  const int x  = rs % W;
  const int b  = rs / W;
  const int xs = max(x - dc, 0);
  const float* Lc = Lp + (long)b * SL + x;
  const float* Rc = Rp + (long)b * SL + xs;
  float* Ob = out1 + ((long)b * H) * W64 + (long)x * 64 + dc;

  float o1p = 0.f, o2 = 0.f;
  int c = 0, a = 0;
  float wc[16], wn[16], oc_[16], op_[16];

#pragma unroll
  for (int j = 0; j < 16; ++j) {
    const long yy = j - 7;
    wc[j] = (j >= 7) ? fabsf(Lc[yy * W] - Rc[yy * W]) : 0.f;
  }
#pragma unroll
  for (int j = 0; j < 16; ++j) {
    const long yy = 9 + j;
    wn[j] = fabsf(Lc[yy * W] - Rc[yy * W]);
  }
  TILE_FULL();
  Ob[0]   = oc_[14];
  Ob[W64] = oc_[15] - oc_[0];
  ROT();

#pragma unroll 1
  for (int tt = 1; tt <= 32; ++tt) {
#pragma unroll
    for (int j = 0; j < 16; ++j) {
      const long yy = 16 * (tt + 1) + j - 7;
      wn[j] = fabsf(Lc[yy * W] - Rc[yy * W]);
    }
    TILE_FULL();
#pragma unroll
    for (int j = 0; j < 16; ++j) {
      const float lo = (j < 15) ? op_[j + 1] : oc_[0];
      const long e = 16 * tt + j - 14;
      Ob[e * W64] = oc_[j] - lo;
    }
    ROT();
  }

#pragma unroll
  for (int j = 0; j < 16; ++j) {
    const long yy = 537 + j;
    wn[j] = (j <= 6) ? fabsf(Lc[yy * W] - Rc[yy * W]) : 0.f;
  }
  TILE_FULL();
#pragma unroll
  for (int j = 0; j < 16; ++j) {
    const float lo = (j < 15) ? op_[j + 1] : oc_[0];
    const long e = 16 * 33 + j - 14;
    Ob[e * W64] = oc_[j] - lo;
  }
  ROT();

  TILE_PART14();
#pragma unroll
  for (int j = 0; j < 14; ++j) {
    const long e = 530 + j;
    Ob[e * W64] = oc_[j] - op_[j + 1];
  }
}

// ---------------------------------------------------------------------------
// Phase 2: horizontal box + argmin. Block = (y, b), 8 waves (512 thr); lane=d.
// r17 structure + explicit tile double-buffer: tile t+1's loads issue before
// tile t's compute (phases A and B), overlapping L3 latency with scan/argmin.
// ---------------------------------------------------------------------------
__global__ __launch_bounds__(512) void hbox_p8(
    const float* __restrict__ out1, int* __restrict__ out) {
  __shared__ float T[61][64];
  const int lane = threadIdx.x & 63;
  const int w    = threadIdx.x >> 6;
  const int y = blockIdx.x, b = blockIdx.y;
  const float* __restrict__ rowp = out1 + ((long)(b * H + y)) * W64 + lane;
  int* __restrict__ orow = out + (long)b * SL + (long)y * W;

  auto ldtile = [&](int t, float (&vv)[16]) {
#pragma unroll
    for (int j = 0; j < 16; ++j) {
      const int xsrc = 16 * t + j - 7;
      vv[j] = (xsrc >= 0 && xsrc < W) ? rowp[(long)xsrc * 64] : 0.f;
    }
  };

  const int t0   = (w < 5) ? 8 * w : 40 + 7 * (w - 5);   // 0,8,16,24,32,40,47,54
  const int tend = t0 + ((w < 5) ? 8 : 7);

  // ---- phase A: owned-tile totals, double-buffered ----
  {
    float va[16], vb[16];
    ldtile(t0, va);
    for (int t = t0; t < tend; ++t) {
      if (t + 1 < tend) ldtile(t + 1, vb);          // issue next tile early
      float s = va[0];
#pragma unroll
      for (int j = 1; j < 16; ++j) s += va[j];
      T[t][lane] = s;
#pragma unroll
      for (int j = 0; j < 16; ++j) va[j] = vb[j];
    }
  }
  __syncthreads();

  // ---- phase B: replay fold, then emit with double-buffered tiles ----
  float o1p = 0.f, o2 = 0.f;
  int c = 0, a = 0;
  for (int tp = 0; tp + 1 < t0; ++tp) fold16(o1p, o2, c, a, T[tp][lane]);

  float va[16], vb[16];
  ldtile(t0, va);                                   // in flight during replay

  float poc[16];
  if (w > 0) {                                      // recompute tile t0-1 scan
    const float base_prev = baseof(o1p, o2, c, a);
    fold16(o1p, o2, c, a, T[t0 - 1][lane]);
    float vv[16];
    ldtile(t0 - 1, vv);
    float ipp = vv[0];
    poc[0] = base_prev + ipp;
#pragma unroll
    for (int j = 1; j < 16; ++j) { ipp += vv[j]; poc[j] = base_prev + ipp; }
  }
  float base = baseof(o1p, o2, c, a);

  for (int t = t0; t < tend; ++t) {
    if (t + 1 < tend) ldtile(t + 1, vb);            // issue next tile early
    float oc_[16];
    float ip = va[0];
    oc_[0] = base + ip;
#pragma unroll
    for (int j = 1; j < 16; ++j) { ip += va[j]; oc_[j] = base + ip; }

    if (t == 0) {
      const float c0 = oc_[14], c1 = oc_[15] - oc_[0];   // e = 0, 1
      float m0 = c0, m1 = c1;
#pragma unroll
      for (int s = 0; s < 6; ++s) {
        const int off = 1 << s;
        m0 = fminf(m0, __shfl_xor(m0, off));
        m1 = fminf(m1, __shfl_xor(m1, off));
      }
      const int d0 = __ffsll((unsigned long long)__ballot(c0 == m0)) - 1;
      const int d1 = __ffsll((unsigned long long)__ballot(c1 == m1)) - 1;
      const int res = (lane == 0) ? d0 : d1;
      if (lane < 2) orow[lane] = res;
    } else if (t == 60) {                           // partial: e = 946..959
      float bc[14], mn[14];
#pragma unroll
      for (int j = 0; j < 14; ++j) { bc[j] = oc_[j] - poc[j + 1]; mn[j] = bc[j]; }
#pragma unroll
      for (int s = 0; s < 6; ++s) {
        const int off = 1 << s;
#pragma unroll
        for (int j = 0; j < 14; ++j) mn[j] = fminf(mn[j], __shfl_xor(mn[j], off));
      }
      int res = 0;
#pragma unroll
      for (int j = 0; j < 14; ++j) {
        const int dj = __ffsll((unsigned long long)__ballot(bc[j] == mn[j])) - 1;
        res = (lane == j) ? dj : res;
      }
      if (lane < 14) orow[946 + lane] = res;
    } else {
      float bc[16], mn[16];
#pragma unroll
      for (int j = 0; j < 16; ++j) {
        bc[j] = oc_[j] - ((j < 15) ? poc[j + 1] : oc_[0]);
        mn[j] = bc[j];
      }
#pragma unroll
      for (int s = 0; s < 6; ++s) {
        const int off = 1 << s;
#pragma unroll
        for (int j = 0; j < 16; ++j) mn[j] = fminf(mn[j], __shfl_xor(mn[j], off));
      }
      int res = 0;
#pragma unroll
      for (int j = 0; j < 16; ++j) {
        const int dj = __ffsll((unsigned long long)__ballot(bc[j] == mn[j])) - 1;
        res = (lane == j) ? dj : res;
      }
      if (lane < 16) orow[16 * t - 14 + lane] = res;
    }

    if (t + 1 < tend) {
      fold16(o1p, o2, c, a, ip);
      base = baseof(o1p, o2, c, a);
#pragma unroll
      for (int j = 0; j < 16; ++j) poc[j] = oc_[j];
#pragma unroll
      for (int j = 0; j < 16; ++j) va[j] = vb[j];
    }
  }
}

extern "C" void kernel_launch(void* const* d_in, const int* in_sizes, int n_in,
                              void* d_out, int out_size, void* d_ws, size_t ws_size,
                              hipStream_t stream) {
  const float* L = (const float*)d_in[0];
  const float* R = (const float*)d_in[1];
  int* out = (int*)d_out;
  if (ws_size < (size_t)(D * SLICE_B)) return;   // direct path confirmed in r12
  float* out1 = (float*)d_ws;

  vbox_t<<<(NB * W * 64) / 256, 256, 0, stream>>>(L, R, out1);
  hbox_p8<<<dim3(H, NB), 512, 0, stream>>>(out1, out);
}

// Round 20
// 167.658 us; speedup vs baseline: 1.3646x; 1.1950x over previous
//
#include <hip/hip_runtime.h>

namespace {
constexpr int H = 544, W = 960, D = 64, NB = 2;
constexpr long SL      = (long)H * W;     // per-batch image elems
constexpr long SLICE_B = (long)NB * SL * 4;
constexpr long W64     = (long)W * 64;    // row stride in out1 elems
}

// ===========================================================================
// Bitwise replica of XLA ReduceWindowRewriter base-16 cumsum (verified
// r12-r19). Linear out1 layout [b][y][x][d].
// ===========================================================================

__device__ __forceinline__ void fold16(float& o1p, float& o2, int& c, int& a,
                                       float tot) {
  o1p = (c == 0) ? tot : (o1p + tot);
  if (++c == 16) { o2 = (a == 0) ? o1p : (o2 + o1p); ++a; c = 0; }
}
__device__ __forceinline__ float baseof(float o1p, float o2, int c, int a) {
  return (a == 0) ? ((c == 0) ? 0.f : o1p) : ((c == 0) ? o2 : (o2 + o1p));
}

#define TILE_FULL()                                                          \
  {                                                                          \
    const float base =                                                       \
        (a == 0) ? ((c == 0) ? 0.f : o1p) : ((c == 0) ? o2 : (o2 + o1p));    \
    float ip = wc[0];                                                        \
    oc_[0] = base + ip;                                                      \
    _Pragma("unroll") for (int j = 1; j < 16; ++j) {                         \
      ip += wc[j];                                                           \
      oc_[j] = base + ip;                                                    \
    }                                                                        \
    o1p = (c == 0) ? ip : (o1p + ip);                                        \
    if (++c == 16) { o2 = (a == 0) ? o1p : (o2 + o1p); ++a; c = 0; }         \
  }

#define TILE_PART14()                                                        \
  {                                                                          \
    const float base =                                                       \
        (a == 0) ? ((c == 0) ? 0.f : o1p) : ((c == 0) ? o2 : (o2 + o1p));    \
    float ip = wc[0];                                                        \
    oc_[0] = base + ip;                                                      \
    _Pragma("unroll") for (int j = 1; j < 14; ++j) {                         \
      ip += wc[j];                                                           \
      oc_[j] = base + ip;                                                    \
    }                                                                        \
  }

#define ROT()                                                                \
  _Pragma("unroll") for (int j = 0; j < 16; ++j) {                           \
    op_[j] = oc_[j];                                                         \
    wc[j] = wn[j];                                                           \
  }

// ---------------------------------------------------------------------------
// Phase 1: vertical box -> out1[b][y][x][d]. Thread = (b, x, lane=d).
// Verbatim r13 kernel (verified 74 us @ 3.6 TB/s dense writes).
// ---------------------------------------------------------------------------
__global__ __launch_bounds__(256) void vbox_t(
    const float* __restrict__ Lp, const float* __restrict__ Rp,
    float* __restrict__ out1) {
  const int t  = blockIdx.x * 256 + threadIdx.x;
  const int dc = t & 63;
  const int rs = t >> 6;
  const int x  = rs % W;
  const int b  = rs / W;
  const int xs = max(x - dc, 0);
  const float* Lc = Lp + (long)b * SL + x;
  const float* Rc = Rp + (long)b * SL + xs;
  float* Ob = out1 + ((long)b * H) * W64 + (long)x * 64 + dc;

  float o1p = 0.f, o2 = 0.f;
  int c = 0, a = 0;
  float wc[16], wn[16], oc_[16], op_[16];

#pragma unroll
  for (int j = 0; j < 16; ++j) {
    const long yy = j - 7;
    wc[j] = (j >= 7) ? fabsf(Lc[yy * W] - Rc[yy * W]) : 0.f;
  }
#pragma unroll
  for (int j = 0; j < 16; ++j) {
    const long yy = 9 + j;
    wn[j] = fabsf(Lc[yy * W] - Rc[yy * W]);
  }
  TILE_FULL();
  Ob[0]   = oc_[14];
  Ob[W64] = oc_[15] - oc_[0];
  ROT();

#pragma unroll 1
  for (int tt = 1; tt <= 32; ++tt) {
#pragma unroll
    for (int j = 0; j < 16; ++j) {
      const long yy = 16 * (tt + 1) + j - 7;
      wn[j] = fabsf(Lc[yy * W] - Rc[yy * W]);
    }
    TILE_FULL();
#pragma unroll
    for (int j = 0; j < 16; ++j) {
      const float lo = (j < 15) ? op_[j + 1] : oc_[0];
      const long e = 16 * tt + j - 14;
      Ob[e * W64] = oc_[j] - lo;
    }
    ROT();
  }

#pragma unroll
  for (int j = 0; j < 16; ++j) {
    const long yy = 537 + j;
    wn[j] = (j <= 6) ? fabsf(Lc[yy * W] - Rc[yy * W]) : 0.f;
  }
  TILE_FULL();
#pragma unroll
  for (int j = 0; j < 16; ++j) {
    const float lo = (j < 15) ? op_[j + 1] : oc_[0];
    const long e = 16 * 33 + j - 14;
    Ob[e * W64] = oc_[j] - lo;
  }
  ROT();

  TILE_PART14();
#pragma unroll
  for (int j = 0; j < 14; ++j) {
    const long e = 530 + j;
    Ob[e * W64] = oc_[j] - op_[j + 1];
  }
}

// ---------------------------------------------------------------------------
// Phase 2: horizontal box + argmin. Block = (y, b), 8 waves (512 thr); lane=d.
// Scan machinery identical to r17 (verified). Argmin replaced by per-wave
// LDS transpose: wave writes cost[j][d], lane (x=lane&15, g=lane>>4) scans
// its x-row's 16-d group (ascending k, strict < = first-min), then 2-stage
// lexicographic (cost,d) merge across the 4 ascending d-groups. Same values,
// same first-occurrence semantics => bitwise-identical result.
// LDS: T[61][64] (phase A + replay) overlaid by cl[8][16][68] after a
// barrier (T is dead once replay completes).
// ---------------------------------------------------------------------------
__global__ __launch_bounds__(512) void hbox_p8(
    const float* __restrict__ out1, int* __restrict__ out) {
  __shared__ float lds[8 * 16 * 68];               // 34.8 KB union
  float (*T)[64] = reinterpret_cast<float (*)[64]>(lds);   // first 3904 floats
  const int lane = threadIdx.x & 63;
  const int w    = threadIdx.x >> 6;
  float* clw = lds + w * (16 * 68);                // per-wave cost tile
  const int y = blockIdx.x, b = blockIdx.y;
  const float* __restrict__ rowp = out1 + ((long)(b * H + y)) * W64 + lane;
  int* __restrict__ orow = out + (long)b * SL + (long)y * W;

  auto ldtile = [&](int t, float (&vv)[16]) {
#pragma unroll
    for (int j = 0; j < 16; ++j) {
      const int xsrc = 16 * t + j - 7;
      vv[j] = (xsrc >= 0 && xsrc < W) ? rowp[(long)xsrc * 64] : 0.f;
    }
  };

  const int t0   = (w < 5) ? 8 * w : 40 + 7 * (w - 5);   // 0,8,16,24,32,40,47,54
  const int tend = t0 + ((w < 5) ? 8 : 7);

  // ---- phase A: owned-tile totals (identical 16-add order) ----
  for (int t = t0; t < tend; ++t) {
    float vv[16];
    ldtile(t, vv);
    float s = vv[0];
#pragma unroll
    for (int j = 1; j < 16; ++j) s += vv[j];
    T[t][lane] = s;
  }
  __syncthreads();

  // ---- replay fold to entry state (T still live) ----
  float o1p = 0.f, o2 = 0.f;
  int c = 0, a = 0;
  for (int tp = 0; tp + 1 < t0; ++tp) fold16(o1p, o2, c, a, T[tp][lane]);

  float poc[16];
  if (w > 0) {                                     // recompute tile t0-1 scan
    const float base_prev = baseof(o1p, o2, c, a);
    fold16(o1p, o2, c, a, T[t0 - 1][lane]);
    float vv[16];
    ldtile(t0 - 1, vv);
    float ipp = vv[0];
    poc[0] = base_prev + ipp;
#pragma unroll
    for (int j = 1; j < 16; ++j) { ipp += vv[j]; poc[j] = base_prev + ipp; }
  }
  float base = baseof(o1p, o2, c, a);
  __syncthreads();                                 // T dead -> cl region live

  const int xsl = lane & 15, g = lane >> 4;
  float* rdp = clw + xsl * 68 + g * 16;            // this lane's read base

  for (int t = t0; t < tend; ++t) {
    float vv[16];
    ldtile(t, vv);
    float oc_[16];
    float ip = vv[0];
    oc_[0] = base + ip;
#pragma unroll
    for (int j = 1; j < 16; ++j) { ip += vv[j]; oc_[j] = base + ip; }

    // cost per x-slot -> LDS (slots without a real output get a sentinel)
    if (t == 0) {
      clw[0 * 68 + lane] = oc_[14];                // e = 0 (lo = 0)
      clw[1 * 68 + lane] = oc_[15] - oc_[0];       // e = 1
#pragma unroll
      for (int j = 2; j < 16; ++j) clw[j * 68 + lane] = 3.0e38f;
    } else if (t == 60) {
#pragma unroll
      for (int j = 0; j < 14; ++j) clw[j * 68 + lane] = oc_[j] - poc[j + 1];
      clw[14 * 68 + lane] = 3.0e38f;
      clw[15 * 68 + lane] = 3.0e38f;
    } else {
#pragma unroll
      for (int j = 0; j < 16; ++j)
        clw[j * 68 + lane] = oc_[j] - ((j < 15) ? poc[j + 1] : oc_[0]);
    }

    // in-group argmin: lane scans d = 16g..16g+15 of its x-slot (ascending,
    // strict < = first-min). Reads are within-wave (no barrier needed).
    const float4 f0 = *reinterpret_cast<const float4*>(rdp);
    const float4 f1 = *reinterpret_cast<const float4*>(rdp + 4);
    const float4 f2 = *reinterpret_cast<const float4*>(rdp + 8);
    const float4 f3 = *reinterpret_cast<const float4*>(rdp + 12);
    const float vals[16] = {f0.x, f0.y, f0.z, f0.w, f1.x, f1.y, f1.z, f1.w,
                            f2.x, f2.y, f2.z, f2.w, f3.x, f3.y, f3.z, f3.w};
    float m = vals[0];
    int  md = 16 * g;
#pragma unroll
    for (int k = 1; k < 16; ++k)
      if (vals[k] < m) { m = vals[k]; md = 16 * g + k; }

    // cross-group lexicographic merge (groups ascending in d)
#pragma unroll
    for (int off = 16; off <= 32; off <<= 1) {
      const float om  = __shfl_xor(m, off);
      const int   omd = __shfl_xor(md, off);
      if (om < m || (om == m && omd < md)) { m = om; md = omd; }
    }

    if (t == 0)       { if (lane < 2)  orow[lane] = md; }
    else if (t == 60) { if (lane < 14) orow[946 + lane] = md; }
    else              { if (lane < 16) orow[16 * t - 14 + lane] = md; }

    if (t + 1 < tend) {
      fold16(o1p, o2, c, a, ip);
      base = baseof(o1p, o2, c, a);
#pragma unroll
      for (int j = 0; j < 16; ++j) poc[j] = oc_[j];
    }
  }
}

extern "C" void kernel_launch(void* const* d_in, const int* in_sizes, int n_in,
                              void* d_out, int out_size, void* d_ws, size_t ws_size,
                              hipStream_t stream) {
  const float* L = (const float*)d_in[0];
  const float* R = (const float*)d_in[1];
  int* out = (int*)d_out;
  if (ws_size < (size_t)(D * SLICE_B)) return;   // direct path confirmed in r12
  float* out1 = (float*)d_ws;

  vbox_t<<<(NB * W * 64) / 256, 256, 0, stream>>>(L, R, out1);
  hbox_p8<<<dim3(H, NB), 512, 0, stream>>>(out1, out);
}